// Round 5
// baseline (842.507 us; speedup 1.0000x reference)
//
#include <hip/hip_runtime.h>

// Problem constants
#define Bv    32
#define Lv    512
#define Hv    512
#define Fv    512
#define Tv    4096
#define Mv    (Bv*Lv)          // 16384 rows
#define NBINSv 256

// d_out layout (floats): out(B,T,H) | pit(B,L) | eng(B,L) | log_dur(B,L) | mel_len(B)
#define OUT_OFF 0
#define PIT_OFF (Bv*(size_t)Tv*Hv)              // 67108864
#define ENG_OFF (PIT_OFF + Mv)
#define DUR_OFF (ENG_OFF + Mv)
#define MEL_OFF (DUR_OFF + Mv)

typedef unsigned short ushort;
typedef __attribute__((ext_vector_type(8))) short   bf16x8;   // 8 bf16 in 4 VGPRs
typedef __attribute__((ext_vector_type(4))) float   f32x4;
typedef __attribute__((ext_vector_type(8))) unsigned short u16x8;

__device__ __forceinline__ float b2f(ushort u) {
    union { float f; unsigned u; } x; x.u = ((unsigned)u) << 16; return x.f;
}
__device__ __forceinline__ ushort f2b(float f) {
    union { float f; unsigned u; } x; x.f = f;
    unsigned r = x.u + 0x7fffu + ((x.u >> 16) & 1u);   // RNE
    return (ushort)(r >> 16);
}

#define GLL16(g, l) __builtin_amdgcn_global_load_lds( \
    (const __attribute__((address_space(1))) void*)(g), \
    (__attribute__((address_space(3))) void*)(l), 16, 0, 0)

// Struct-of-pointers kernel args for z-batched launches
template<int NZ> struct GArgs {
    const ushort* A[NZ];
    const ushort* W[NZ];
    const float*  bias[NZ];
    ushort*       C[NZ];
};
struct RmsArgs   { const ushort* h[3]; const float* g[3]; ushort* o[3]; };
struct RlArgs    { const ushort* h[3]; const float* g[3]; const float* wl[3]; const float* bl[3]; };
struct TransArgs { const float* src[6]; ushort* dst[6]; };
struct ConvArgs  { const float* src[2]; ushort* dst[2]; };

// ---------------------------------------------------------------------------
// bf16 MFMA GEMM, z-batched.  C[m,n] = epi( sum A*Wt + bias )
// R0-proven structure: tile 128x128, BK=32, 256 thr = 4 waves, 4x4 16x16x32
// MFMA tiles / wave, ~3 blocks/CU (TLP hides barrier drains).
// R4: T1 chunked XCD swizzle (kept; bit-identical relabeling).
// R5: vectorized epilogue — acc slices are transposed through LDS
// (cs[32][132], 2-way-conflict writes = free) so bias/res/pe/ee loads and
// the C store are fully coalesced float4 / ushort8 ops instead of 64 scalar
// 2B stores + up to 192 scalar gather loads per thread.  Same per-element
// arithmetic and K-order -> bit-identical output.
// NTAPS=3 folds K=3 conv taps (zero pad via zero-page redirect).
// EPI: 0 relu; 1 relu+res; 2 relu+res+pe+ee; 3 runtime per-z (z==2 ? 2 : 1)
// ---------------------------------------------------------------------------
template<int NTAPS, int EPI, int NZ>
__global__ __launch_bounds__(256) void gemm_bf16_kernel(
    GArgs<NZ> ga, const float* __restrict__ res, const float* __restrict__ pe,
    const float* __restrict__ ee, const int* __restrict__ idxp,
    const int* __restrict__ idxe, const ushort* __restrict__ zp)
{
    constexpr int KTOT = NTAPS * 512;
    constexpr int GX   = Fv / 128;           // 4
    constexpr int GY   = Mv / 128;           // 128
    constexpr int NWG  = GX * GY * NZ;       // % 8 == 0 always

    // ---- T1 chunked XCD swizzle (bijective) ----
    int lin = blockIdx.x + GX * (blockIdx.y + GY * blockIdx.z);
    lin = (lin & 7) * (NWG >> 3) + (lin >> 3);
    const int bx = lin & (GX - 1);
    const int by = (lin >> 2) & (GY - 1);
    const int z  = (NZ > 1) ? (lin / (GX * GY)) : 0;

    const ushort* __restrict__ A    = ga.A[z];
    const ushort* __restrict__ Bt   = ga.W[z];
    const float*  __restrict__ bias = ga.bias[z];
    ushort*       __restrict__ C    = ga.C[z];

    __shared__ ushort As[128 * 32];
    __shared__ ushort Bs[128 * 32];
    __shared__ float  cs[32][132];           // epilogue transpose staging

    const int tid = threadIdx.x;
    const int n0 = bx * 128;
    const int m0 = by * 128;

    const int sar = tid >> 2;       // staging row
    const int sl  = tid & 3;        // staging 16B slot

    const int lane = tid & 63;
    const int w    = tid >> 6;
    const int wm   = (w & 1) * 64;
    const int wn   = (w >> 1) * 64;
    const int lr   = lane & 15;
    const int q    = lane >> 4;

    f32x4 acc[4][4];
    #pragma unroll
    for (int i = 0; i < 4; ++i)
        #pragma unroll
        for (int j = 0; j < 4; ++j) {
            f32x4 zz = {0.f, 0.f, 0.f, 0.f};
            acc[i][j] = zz;
        }

    for (int kt = 0; kt < NTAPS * 16; ++kt) {
        const int tap = (NTAPS == 3) ? (kt >> 4) : 0;
        const int kin = (NTAPS == 3) ? ((kt & 15) << 5) : (kt << 5);

        #pragma unroll
        for (int r = 0; r < 2; ++r) {
            const int row = sar + r * 64;
            const int m   = m0 + row;
            const int qg  = (sl - (row >> 1)) & 3;
            const ushort* asrc;
            if (NTAPS == 3) {
                const int l  = m & (Lv - 1);
                const int ls = l + tap - 1;
                asrc = ((unsigned)ls < (unsigned)Lv)
                     ? A + (size_t)(m + tap - 1) * 512 + kin + qg * 8
                     : zp;
            } else {
                asrc = A + (size_t)m * 512 + kin + qg * 8;
            }
            GLL16(asrc, &As[row * 32 + sl * 8]);
            const ushort* bsrc = Bt + (size_t)(n0 + row) * KTOT + tap * 512 + kin + qg * 8;
            GLL16(bsrc, &Bs[row * 32 + sl * 8]);
        }
        __syncthreads();

        bf16x8 af[4], bfr[4];
        #pragma unroll
        for (int i = 0; i < 4; ++i) {
            const int rm = wm + i * 16 + lr;
            af[i]  = *(const bf16x8*)&As[rm * 32 + (((q + (rm >> 1)) & 3) << 3)];
            const int rn = wn + i * 16 + lr;
            bfr[i] = *(const bf16x8*)&Bs[rn * 32 + (((q + (rn >> 1)) & 3) << 3)];
        }
        #pragma unroll
        for (int i = 0; i < 4; ++i)
            #pragma unroll
            for (int j = 0; j < 4; ++j)
                acc[i][j] = __builtin_amdgcn_mfma_f32_16x16x32_bf16(
                                af[i], bfr[j], acc[i][j], 0, 0, 0);
        __syncthreads();
    }

    // ---- vectorized epilogue via LDS transpose ----
    // writer: cs[band + q*4 + r][wn + j*16 + lr] = acc[i][j][r]
    //   (band 0/16 for wm 0/64; covers rows of quadrant i, all 128 cols)
    // reader: thread t -> row rr = t>>3 (0..31), cols cc = (t&7)*16 .. +15
    //   global m = m0 + i*16 + rr + (rr>=16 ? 48 : 0); fully coalesced I/O.
    int epi = EPI;
    if (EPI == 3) epi = (z == 2) ? 2 : 1;
    const int band = (w & 1) * 16;
    const int rr   = tid >> 3;
    const int cc   = (tid & 7) * 16;

    float bb[16];
    #pragma unroll
    for (int k = 0; k < 4; ++k) {
        const float4 t4 = *(const float4*)&bias[n0 + cc + 4 * k];
        bb[4*k] = t4.x; bb[4*k+1] = t4.y; bb[4*k+2] = t4.z; bb[4*k+3] = t4.w;
    }

    #pragma unroll
    for (int i = 0; i < 4; ++i) {
        __syncthreads();                      // prior i's reads complete
        #pragma unroll
        for (int j = 0; j < 4; ++j)
            #pragma unroll
            for (int r = 0; r < 4; ++r)
                cs[band + q * 4 + r][wn + j * 16 + lr] = acc[i][j][r];
        __syncthreads();

        const int m = m0 + i * 16 + rr + ((rr & 16) ? 48 : 0);
        const size_t ro = (size_t)m * 512 + n0 + cc;

        float vv[16];
        #pragma unroll
        for (int k = 0; k < 4; ++k) {
            const float4 a4 = *(const float4*)&cs[rr][cc + 4 * k];
            vv[4*k] = a4.x; vv[4*k+1] = a4.y; vv[4*k+2] = a4.z; vv[4*k+3] = a4.w;
        }
        #pragma unroll
        for (int k = 0; k < 16; ++k) vv[k] = fmaxf(vv[k] + bb[k], 0.f);

        if (EPI != 0 && epi >= 1) {
            #pragma unroll
            for (int k = 0; k < 4; ++k) {
                const float4 r4 = *(const float4*)&res[ro + 4 * k];
                vv[4*k] += r4.x; vv[4*k+1] += r4.y; vv[4*k+2] += r4.z; vv[4*k+3] += r4.w;
            }
        }
        if (EPI >= 2 && epi == 2) {
            const size_t po = (size_t)idxp[m] * 512 + n0 + cc;
            const size_t eo = (size_t)idxe[m] * 512 + n0 + cc;
            #pragma unroll
            for (int k = 0; k < 4; ++k) {
                const float4 p4 = *(const float4*)&pe[po + 4 * k];
                const float4 e4 = *(const float4*)&ee[eo + 4 * k];
                vv[4*k]   += p4.x + e4.x; vv[4*k+1] += p4.y + e4.y;
                vv[4*k+2] += p4.z + e4.z; vv[4*k+3] += p4.w + e4.w;
            }
        }

        u16x8 o0, o1;
        #pragma unroll
        for (int k = 0; k < 8; ++k) { o0[k] = f2b(vv[k]); o1[k] = f2b(vv[8 + k]); }
        *(u16x8*)(C + ro)     = o0;
        *(u16x8*)(C + ro + 8) = o1;
    }
}

// ---------------------------------------------------------------------------
// fp32 -> bf16 convert, z-batched over {x, emb}
// ---------------------------------------------------------------------------
__global__ __launch_bounds__(256) void convert_kernel(ConvArgs ca)
{
    const float* __restrict__ X  = ca.src[blockIdx.y];
    ushort*      __restrict__ Xb = ca.dst[blockIdx.y];
    const size_t i = (size_t)blockIdx.x * 256 + threadIdx.x;
    const float4 a = ((const float4*)X)[2 * i];
    const float4 b = ((const float4*)X)[2 * i + 1];
    u16x8 o;
    o[0] = f2b(a.x); o[1] = f2b(a.y); o[2] = f2b(a.z); o[3] = f2b(a.w);
    o[4] = f2b(b.x); o[5] = f2b(b.y); o[6] = f2b(b.z); o[7] = f2b(b.w);
    *(u16x8*)(Xb + i * 8) = o;
}

// ---------------------------------------------------------------------------
// Weight transpose+convert, z-batched: W[kk][n] fp32 -> Wt[n][kk] bf16
// ---------------------------------------------------------------------------
__global__ __launch_bounds__(256) void transpose_kernel(TransArgs ta, int Ktot)
{
    const float* __restrict__ W  = ta.src[blockIdx.z];
    ushort*      __restrict__ Wt = ta.dst[blockIdx.z];
    __shared__ float t[32][33];
    const int k0 = blockIdx.x * 32, n0 = blockIdx.y * 32;
    const int r = threadIdx.x >> 5, c = threadIdx.x & 31;
    #pragma unroll
    for (int rr = 0; rr < 4; ++rr)
        t[r + rr * 8][c] = W[(size_t)(k0 + r + rr * 8) * 512 + n0 + c];
    __syncthreads();
    #pragma unroll
    for (int rr = 0; rr < 4; ++rr)
        Wt[(size_t)(n0 + r + rr * 8) * Ktot + k0 + c] = f2b(t[c][r + rr * 8]);
}

// ---------------------------------------------------------------------------
// RMSNorm, z-batched (grid.y = chain). bf16 in/out, fp32 math.
// ---------------------------------------------------------------------------
__global__ __launch_bounds__(128) void rms_kernel(RmsArgs ra)
{
    const int z = blockIdx.y;
    const int row = blockIdx.x;
    const int tid = threadIdx.x;
    const ushort* __restrict__ h = ra.h[z];
    const ushort4 hv = ((const ushort4*)(h + (size_t)row * 512))[tid];
    const float v0 = b2f(hv.x), v1 = b2f(hv.y), v2 = b2f(hv.z), v3 = b2f(hv.w);
    float ss = v0 * v0 + v1 * v1 + v2 * v2 + v3 * v3;
    #pragma unroll
    for (int off = 32; off; off >>= 1) ss += __shfl_down(ss, off, 64);
    __shared__ float p[2];
    if ((tid & 63) == 0) p[tid >> 6] = ss;
    __syncthreads();
    const float tot = p[0] + p[1];
    const float inv = 1.f / (sqrtf(tot * (1.f / 512.f)) + 1e-8f);
    const float4 gv = ((const float4*)ra.g[z])[tid];
    ushort4 ov;
    ov.x = f2b(gv.x * v0 * inv); ov.y = f2b(gv.y * v1 * inv);
    ov.z = f2b(gv.z * v2 * inv); ov.w = f2b(gv.w * v3 * inv);
    ((ushort4*)(ra.o[z] + (size_t)row * 512))[tid] = ov;
}

// ---------------------------------------------------------------------------
// Fused RMSNorm + linear head, z-batched. pred = mask ? 0 : inv*sum(g*h*wl)+bl
// ---------------------------------------------------------------------------
__global__ __launch_bounds__(256) void rmslin_kernel(
    RlArgs ra, const unsigned char* __restrict__ mask, float* __restrict__ predbase)
{
    const int z = blockIdx.y;
    const int wave = threadIdx.x >> 6, lane = threadIdx.x & 63;
    const int row = blockIdx.x * 4 + wave;
    const ushort* __restrict__ h = ra.h[z];
    const bf16x8 hv = *(const bf16x8*)(h + (size_t)row * 512 + lane * 8);
    const float4 g0 = *(const float4*)(ra.g[z] + lane * 8);
    const float4 g1 = *(const float4*)(ra.g[z] + lane * 8 + 4);
    const float4 w0 = *(const float4*)(ra.wl[z] + lane * 8);
    const float4 w1 = *(const float4*)(ra.wl[z] + lane * 8 + 4);
    float hf[8];
    #pragma unroll
    for (int t = 0; t < 8; ++t) hf[t] = b2f((ushort)hv[t]);
    float ss = 0.f, sgw = 0.f;
    #pragma unroll
    for (int t = 0; t < 8; ++t) ss += hf[t] * hf[t];
    sgw += hf[0]*g0.x*w0.x + hf[1]*g0.y*w0.y + hf[2]*g0.z*w0.z + hf[3]*g0.w*w0.w;
    sgw += hf[4]*g1.x*w1.x + hf[5]*g1.y*w1.y + hf[6]*g1.z*w1.z + hf[7]*g1.w*w1.w;
    #pragma unroll
    for (int off = 32; off; off >>= 1) {
        ss  += __shfl_down(ss,  off, 64);
        sgw += __shfl_down(sgw, off, 64);
    }
    if (lane == 0) {
        const float inv = 1.f / (sqrtf(ss * (1.f / 512.f)) + 1e-8f);
        predbase[(size_t)z * Mv + row] = mask[row] ? 0.f : (sgw * inv + ra.bl[z][0]);
    }
}

// ---------------------------------------------------------------------------
// searchsorted(bins, v, 'left') for pitch & energy targets
// ---------------------------------------------------------------------------
__global__ __launch_bounds__(256) void idx_kernel(
    const float* __restrict__ pt, const float* __restrict__ et,
    const float* __restrict__ pbins, const float* __restrict__ ebins,
    int* __restrict__ idxp, int* __restrict__ idxe)
{
    __shared__ float pb[NBINSv - 1], ebn[NBINSv - 1];
    const int tid = threadIdx.x;
    if (tid < NBINSv - 1) { pb[tid] = pbins[tid]; ebn[tid] = ebins[tid]; }
    __syncthreads();
    const int m = blockIdx.x * 256 + tid;
    const float pv = pt[m], ev = et[m];
    int lo = 0, hi = NBINSv - 1;
    while (lo < hi) { int mid = (lo + hi) >> 1; if (pb[mid] < pv) lo = mid + 1; else hi = mid; }
    idxp[m] = lo;
    lo = 0; hi = NBINSv - 1;
    while (lo < hi) { int mid = (lo + hi) >> 1; if (ebn[mid] < ev) lo = mid + 1; else hi = mid; }
    idxe[m] = lo;
}

// ---------------------------------------------------------------------------
// Per-batch inclusive cumsum of durations, plus mel_len
// ---------------------------------------------------------------------------
__global__ __launch_bounds__(512) void cumsum_kernel(
    const int* __restrict__ dur, int* __restrict__ cum,
    int* __restrict__ melint, float* __restrict__ melout)
{
    __shared__ int s[Lv];
    const int b = blockIdx.x, tid = threadIdx.x;
    s[tid] = dur[b * Lv + tid];
    __syncthreads();
    for (int off = 1; off < Lv; off <<= 1) {
        int t = (tid >= off) ? s[tid - off] : 0;
        __syncthreads();
        s[tid] += t;
        __syncthreads();
    }
    cum[b * Lv + tid] = s[tid];
    if (tid == Lv - 1) { melint[b] = s[tid]; melout[b] = (float)s[tid]; }
}

// ---------------------------------------------------------------------------
// Precompute regulate source map: tmap[b,t] = t < mel_len[b] ? src_row : -1
// ---------------------------------------------------------------------------
__global__ __launch_bounds__(256) void tmap_kernel(
    const int* __restrict__ cum, const int* __restrict__ melint,
    int* __restrict__ tmap)
{
    const int bt = blockIdx.x * 256 + threadIdx.x;
    const int b = bt >> 12;
    const int t = bt & (Tv - 1);
    const int* c = cum + b * Lv;
    int lo = 0, hi = Lv;
    while (lo < hi) { int mid = (lo + hi) >> 1; if (c[mid] <= t) lo = mid + 1; else hi = mid; }
    tmap[bt] = (t < melint[b]) ? (b * Lv + min(lo, Lv - 1)) : -1;
}

// ---------------------------------------------------------------------------
// Length regulate gather: out[bt,:] = tmap[bt] >= 0 ? xo[tmap[bt],:] : 0
// ---------------------------------------------------------------------------
__global__ __launch_bounds__(128) void regulate_kernel(
    const ushort* __restrict__ xo, const int* __restrict__ tmap,
    float* __restrict__ out)
{
    const int bt = blockIdx.x;
    const int src = tmap[bt];
    float4 v = make_float4(0.f, 0.f, 0.f, 0.f);
    if (src >= 0) {
        const ushort4 u = ((const ushort4*)(xo + (size_t)src * 512))[threadIdx.x];
        v.x = b2f(u.x); v.y = b2f(u.y); v.z = b2f(u.z); v.w = b2f(u.w);
    }
    ((float4*)(out + (size_t)bt * 512))[threadIdx.x] = v;
}

// ---------------------------------------------------------------------------
extern "C" void kernel_launch(void* const* d_in, const int* in_sizes, int n_in,
                              void* d_out, int out_size, void* d_ws, size_t ws_size,
                              hipStream_t stream)
{
    const float* x    = (const float*)d_in[0];
    const float* emb  = (const float*)d_in[1];
    const unsigned char* mask = (const unsigned char*)d_in[2];
    const int*   durt = (const int*)d_in[3];
    const float* pt   = (const float*)d_in[4];
    const float* et   = (const float*)d_in[5];
    const float* dw1 = (const float*)d_in[7],  *db1 = (const float*)d_in[8],
               * dg1 = (const float*)d_in[9],  *dw2 = (const float*)d_in[10],
               * db2 = (const float*)d_in[11], *dg2 = (const float*)d_in[12],
               * dwl = (const float*)d_in[13], *dbl = (const float*)d_in[14];
    const float* pw1 = (const float*)d_in[15], *pb1 = (const float*)d_in[16],
               * pg1 = (const float*)d_in[17], *pw2 = (const float*)d_in[18],
               * pb2 = (const float*)d_in[19], *pg2 = (const float*)d_in[20],
               * pwl = (const float*)d_in[21], *pbl = (const float*)d_in[22];
    const float* ew1 = (const float*)d_in[23], *eb1 = (const float*)d_in[24],
               * eg1 = (const float*)d_in[25], *ew2 = (const float*)d_in[26],
               * eb2 = (const float*)d_in[27], *eg2 = (const float*)d_in[28],
               * ewl = (const float*)d_in[29], *ebl = (const float*)d_in[30];
    const float* ppw1 = (const float*)d_in[31], *ppb1 = (const float*)d_in[32],
               * ppw2 = (const float*)d_in[33], *ppb2 = (const float*)d_in[34];
    const float* epw1 = (const float*)d_in[35], *epb1 = (const float*)d_in[36],
               * epw2 = (const float*)d_in[37], *epb2 = (const float*)d_in[38];
    const float* spw1 = (const float*)d_in[39], *spb1 = (const float*)d_in[40],
               * spw2 = (const float*)d_in[41], *spb2 = (const float*)d_in[42];
    const float* pbins = (const float*)d_in[43];
    const float* ebins = (const float*)d_in[44];
    const float* pemb  = (const float*)d_in[45];
    const float* eemb  = (const float*)d_in[46];

    float* outf = (float*)d_out;

    // ---- ws scratch (int offsets) ----
    int*    cum    = (int*)d_ws;                    // 16384
    int*    melint = cum + 16384;                   // 64
    int*    idxp   = melint + 64;                   // 16384
    int*    idxe   = idxp + 16384;                  // 16384
    ushort* zp     = (ushort*)(idxe + 16384);       // 32 ushorts (16B-aligned)
    int*    tmap   = idxe + 16448;                  // 131072
    ushort* xob    = (ushort*)((float*)d_ws + 262144);  // Mv*512 bf16, 1MB offset

    // ---- d_out front scratch (float offsets; regulate overwrites all) ----
    #define OBUF(i) ((ushort*)(outf + (size_t)(i) * 4194304))
    ushort* xb  = OBUF(0);   ushort* eb  = OBUF(1);
    ushort* pA0 = OBUF(2);   ushort* pA1 = OBUF(3);  ushort* pA2 = OBUF(4);
    ushort* xp  = OBUF(5);   ushort* xe  = OBUF(6);
    ushort* c0  = OBUF(7);   ushort* c1  = OBUF(8);  ushort* c2  = OBUF(9);
    ushort* r0  = OBUF(10);  ushort* r1  = OBUF(11); ushort* r2  = OBUF(12);
    ushort* wt[12];
    {
        size_t off = 13ull * 4194304;
        for (int i = 0; i < 6; ++i)  { wt[i] = (ushort*)(outf + off); off += 393216; }  // conv 1536x512
        for (int i = 6; i < 12; ++i) { wt[i] = (ushort*)(outf + off); off += 131072; }  // proj 512x512
    }

    hipMemsetAsync(zp, 0, 64, stream);

    // converts + transposes (batched)
    { ConvArgs ca = {{x, emb}, {xb, eb}};
      convert_kernel<<<dim3(4096, 2), 256, 0, stream>>>(ca); }
    { TransArgs ta = {{dw1, dw2, pw1, pw2, ew1, ew2}, {wt[0], wt[1], wt[2], wt[3], wt[4], wt[5]}};
      transpose_kernel<<<dim3(48, 16, 6), 256, 0, stream>>>(ta, 1536); }
    { TransArgs ta = {{ppw1, ppw2, epw1, epw2, spw1, spw2},
                      {wt[6], wt[7], wt[8], wt[9], wt[10], wt[11]}};
      transpose_kernel<<<dim3(16, 16, 6), 256, 0, stream>>>(ta, 512); }

    idx_kernel<<<Mv / 256, 256, 0, stream>>>(pt, et, pbins, ebins, idxp, idxe);
    cumsum_kernel<<<Bv, Lv, 0, stream>>>(durt, cum, melint, outf + MEL_OFF);
    tmap_kernel<<<Bv * Tv / 256, 256, 0, stream>>>(cum, melint, tmap);

    const dim3 g3(Fv / 128, Mv / 128, 3);   // (4, 128, 3) = 1536 blocks

    // proj1: h = relu(emb @ w1 + b1) for pp/ep/sp
    { GArgs<3> a = {{eb, eb, eb}, {wt[6], wt[8], wt[10]}, {ppb1, epb1, spb1}, {pA0, pA1, pA2}};
      gemm_bf16_kernel<1, 0, 3><<<g3, 256, 0, stream>>>(a, nullptr, nullptr, nullptr,
                                                        nullptr, nullptr, zp); }
    // proj2 merged: pp/ep -> x + relu(h@w2+b2); sp (z==2) adds pe+ee -> xob
    { GArgs<3> a = {{pA0, pA1, pA2}, {wt[7], wt[9], wt[11]}, {ppb2, epb2, spb2}, {xp, xe, xob}};
      gemm_bf16_kernel<1, 3, 3><<<g3, 256, 0, stream>>>(a, x, pemb, eemb,
                                                        idxp, idxe, zp); }

    // conv1 for {pit, eng, dur}
    { GArgs<3> a = {{xp, xe, xb}, {wt[2], wt[4], wt[0]}, {pb1, eb1, db1}, {c0, c1, c2}};
      gemm_bf16_kernel<3, 0, 3><<<g3, 256, 0, stream>>>(a, nullptr, nullptr, nullptr,
                                                        nullptr, nullptr, zp); }
    { RmsArgs ra = {{c0, c1, c2}, {pg1, eg1, dg1}, {r0, r1, r2}};
      rms_kernel<<<dim3(Mv, 3), 128, 0, stream>>>(ra); }
    // conv2
    { GArgs<3> a = {{r0, r1, r2}, {wt[3], wt[5], wt[1]}, {pb2, eb2, db2}, {c0, c1, c2}};
      gemm_bf16_kernel<3, 0, 3><<<g3, 256, 0, stream>>>(a, nullptr, nullptr, nullptr,
                                                        nullptr, nullptr, zp); }
    // fused rms2 + linear head -> preds at PIT|ENG|DUR (contiguous, z-ordered)
    { RlArgs ra = {{c0, c1, c2}, {pg2, eg2, dg2}, {pwl, ewl, dwl}, {pbl, ebl, dbl}};
      rmslin_kernel<<<dim3(Mv / 4, 3), 256, 0, stream>>>(ra, mask, outf + PIT_OFF); }

    // length regulate gather -> out (overwrites all d_out-front scratch)
    regulate_kernel<<<Bv * Tv, 128, 0, stream>>>(xob, tmap, outf + OUT_OFF);
}

// Round 6
// 795.629 us; speedup vs baseline: 1.0589x; 1.0589x over previous
//
#include <hip/hip_runtime.h>

// Problem constants
#define Bv    32
#define Lv    512
#define Hv    512
#define Fv    512
#define Tv    4096
#define Mv    (Bv*Lv)          // 16384 rows
#define NBINSv 256

// d_out layout (floats): out(B,T,H) | pit(B,L) | eng(B,L) | log_dur(B,L) | mel_len(B)
#define OUT_OFF 0
#define PIT_OFF (Bv*(size_t)Tv*Hv)              // 67108864
#define ENG_OFF (PIT_OFF + Mv)
#define DUR_OFF (ENG_OFF + Mv)
#define MEL_OFF (DUR_OFF + Mv)

typedef unsigned short ushort;
typedef __attribute__((ext_vector_type(8))) short   bf16x8;   // 8 bf16 in 4 VGPRs
typedef __attribute__((ext_vector_type(4))) float   f32x4;
typedef __attribute__((ext_vector_type(8))) unsigned short u16x8;

__device__ __forceinline__ float b2f(ushort u) {
    union { float f; unsigned u; } x; x.u = ((unsigned)u) << 16; return x.f;
}
__device__ __forceinline__ ushort f2b(float f) {
    union { float f; unsigned u; } x; x.f = f;
    unsigned r = x.u + 0x7fffu + ((x.u >> 16) & 1u);   // RNE
    return (ushort)(r >> 16);
}

#define GLL16(g, l) __builtin_amdgcn_global_load_lds( \
    (const __attribute__((address_space(1))) void*)(g), \
    (__attribute__((address_space(3))) void*)(l), 16, 0, 0)

// Struct-of-pointers kernel args for z-batched launches
template<int NZ> struct GArgs {
    const ushort* A[NZ];
    const ushort* W[NZ];
    const float*  bias[NZ];
    ushort*       C[NZ];
};
// Epilogue fusion args (RMS folds).  rss: conv1 row sum-of-squares accum.
// inv1: finalized 1/(sqrt(mean)+eps).  ss2/sgw: conv2 rmslin partials.
struct EpiArgs {
    float* rss; const float* inv1; float* ss2; float* sgw;
    const float* g2[3]; const float* wl[3];
};
struct TransArgs { const float* src[6]; const float* gs[6]; ushort* dst[6]; };
struct ConvArgs  { const float* src[2]; ushort* dst[2]; };

// ---------------------------------------------------------------------------
// bf16 MFMA GEMM, z-batched.  C[m,n] = epi( sum A*Wt + bias )
// R0-proven structure: tile 128x128, BK=32, 256 thr = 4 waves, 4x4 16x16x32
// MFMA tiles / wave, 16 KiB LDS -> ~3 blocks/CU (TLP hides barrier drains).
// R4: T1 chunked XCD swizzle (bit-identical relabeling).
// R6: RMS fusion epilogues.
//   EPI 0: relu, write C                                  (proj1)
//   EPI 3: per-z runtime (z==2 ? relu+res+pe+ee : relu+res), write C (proj2)
//   EPI 4: relu, write C, atomic row sum(v^2) -> rss      (conv1; rms1 fold)
//   EPI 5: v = relu(acc*inv1[m]+bias); NO C write; atomic row
//          sum(v^2)->ss2, sum(v*g2[n]*wl[n])->sgw         (conv2; rmslin fold)
// Row reduce: 16 lanes sharing a row shfl_xor-reduce, lr==0 does atomicAdd
// (device-scope, order-nondeterministic ~1ulp).
// NTAPS=3 folds K=3 conv taps (zero pad via zero-page redirect).
// ---------------------------------------------------------------------------
template<int NTAPS, int EPI, int NZ>
__global__ __launch_bounds__(256) void gemm_bf16_kernel(
    GArgs<NZ> ga, EpiArgs ea, const float* __restrict__ res,
    const float* __restrict__ pe, const float* __restrict__ ee,
    const int* __restrict__ idxp, const int* __restrict__ idxe,
    const ushort* __restrict__ zp)
{
    constexpr int KTOT = NTAPS * 512;
    constexpr int GX   = Fv / 128;           // 4
    constexpr int GY   = Mv / 128;           // 128
    constexpr int NWG  = GX * GY * NZ;       // % 8 == 0 always

    // ---- T1 chunked XCD swizzle (bijective) ----
    int lin = blockIdx.x + GX * (blockIdx.y + GY * blockIdx.z);
    lin = (lin & 7) * (NWG >> 3) + (lin >> 3);
    const int bx = lin & (GX - 1);
    const int by = (lin >> 2) & (GY - 1);
    const int z  = (NZ > 1) ? (lin / (GX * GY)) : 0;

    const ushort* __restrict__ A    = ga.A[z];
    const ushort* __restrict__ Bt   = ga.W[z];
    const float*  __restrict__ bias = ga.bias[z];
    ushort*       __restrict__ C    = ga.C[z];

    __shared__ ushort As[128 * 32];
    __shared__ ushort Bs[128 * 32];

    const int tid = threadIdx.x;
    const int n0 = bx * 128;
    const int m0 = by * 128;

    const int sar = tid >> 2;       // staging row
    const int sl  = tid & 3;        // staging 16B slot

    const int lane = tid & 63;
    const int w    = tid >> 6;
    const int wm   = (w & 1) * 64;
    const int wn   = (w >> 1) * 64;
    const int lr   = lane & 15;
    const int q    = lane >> 4;

    f32x4 acc[4][4];
    #pragma unroll
    for (int i = 0; i < 4; ++i)
        #pragma unroll
        for (int j = 0; j < 4; ++j) {
            f32x4 zz = {0.f, 0.f, 0.f, 0.f};
            acc[i][j] = zz;
        }

    for (int kt = 0; kt < NTAPS * 16; ++kt) {
        const int tap = (NTAPS == 3) ? (kt >> 4) : 0;
        const int kin = (NTAPS == 3) ? ((kt & 15) << 5) : (kt << 5);

        #pragma unroll
        for (int r = 0; r < 2; ++r) {
            const int row = sar + r * 64;
            const int m   = m0 + row;
            const int qg  = (sl - (row >> 1)) & 3;
            const ushort* asrc;
            if (NTAPS == 3) {
                const int l  = m & (Lv - 1);
                const int ls = l + tap - 1;
                asrc = ((unsigned)ls < (unsigned)Lv)
                     ? A + (size_t)(m + tap - 1) * 512 + kin + qg * 8
                     : zp;
            } else {
                asrc = A + (size_t)m * 512 + kin + qg * 8;
            }
            GLL16(asrc, &As[row * 32 + sl * 8]);
            const ushort* bsrc = Bt + (size_t)(n0 + row) * KTOT + tap * 512 + kin + qg * 8;
            GLL16(bsrc, &Bs[row * 32 + sl * 8]);
        }
        __syncthreads();

        bf16x8 af[4], bfr[4];
        #pragma unroll
        for (int i = 0; i < 4; ++i) {
            const int rm = wm + i * 16 + lr;
            af[i]  = *(const bf16x8*)&As[rm * 32 + (((q + (rm >> 1)) & 3) << 3)];
            const int rn = wn + i * 16 + lr;
            bfr[i] = *(const bf16x8*)&Bs[rn * 32 + (((q + (rn >> 1)) & 3) << 3)];
        }
        #pragma unroll
        for (int i = 0; i < 4; ++i)
            #pragma unroll
            for (int j = 0; j < 4; ++j)
                acc[i][j] = __builtin_amdgcn_mfma_f32_16x16x32_bf16(
                                af[i], bfr[j], acc[i][j], 0, 0, 0);
        __syncthreads();
    }

    // epilogue: C/D layout col = lane&15 (n), row = q*4 + reg
    int epi = EPI;
    if (EPI == 3) epi = (z == 2) ? 2 : 1;
    #pragma unroll
    for (int i = 0; i < 4; ++i) {
        #pragma unroll
        for (int r = 0; r < 4; ++r) {
            const int m = m0 + wm + i * 16 + q * 4 + r;
            const size_t ro = (size_t)m * 512;
            int ip = 0, ie = 0;
            if (EPI == 3 && epi == 2) { ip = idxp[m]; ie = idxe[m]; }
            float rowinv = 1.f;
            if (EPI == 5) rowinv = ea.inv1[(size_t)z * Mv + m];
            float ssp = 0.f, sgwp = 0.f;
            #pragma unroll
            for (int j = 0; j < 4; ++j) {
                const int n = n0 + wn + j * 16 + lr;
                float v = (EPI == 5) ? (acc[i][j][r] * rowinv + bias[n])
                                     : (acc[i][j][r] + bias[n]);
                v = fmaxf(v, 0.f);
                if (EPI == 3) v += res[ro + n];
                if (EPI == 3 && epi == 2)
                    v += pe[(size_t)ip * 512 + n] + ee[(size_t)ie * 512 + n];
                if (EPI != 5) C[ro + n] = f2b(v);
                if (EPI == 4) ssp += v * v;
                if (EPI == 5) { ssp += v * v; sgwp += v * ea.g2[z][n] * ea.wl[z][n]; }
            }
            if (EPI == 4 || EPI == 5) {
                #pragma unroll
                for (int mm = 1; mm < 16; mm <<= 1) {
                    ssp += __shfl_xor(ssp, mm, 64);
                    if (EPI == 5) sgwp += __shfl_xor(sgwp, mm, 64);
                }
                if (lr == 0) {
                    if (EPI == 4) atomicAdd(&ea.rss[(size_t)z * Mv + m], ssp);
                    if (EPI == 5) {
                        atomicAdd(&ea.ss2[(size_t)z * Mv + m], ssp);
                        atomicAdd(&ea.sgw[(size_t)z * Mv + m], sgwp);
                    }
                }
            }
        }
    }
}

// ---------------------------------------------------------------------------
// fp32 -> bf16 convert, z-batched over {x, emb}
// ---------------------------------------------------------------------------
__global__ __launch_bounds__(256) void convert_kernel(ConvArgs ca)
{
    const float* __restrict__ X  = ca.src[blockIdx.y];
    ushort*      __restrict__ Xb = ca.dst[blockIdx.y];
    const size_t i = (size_t)blockIdx.x * 256 + threadIdx.x;
    const float4 a = ((const float4*)X)[2 * i];
    const float4 b = ((const float4*)X)[2 * i + 1];
    u16x8 o;
    o[0] = f2b(a.x); o[1] = f2b(a.y); o[2] = f2b(a.z); o[3] = f2b(a.w);
    o[4] = f2b(b.x); o[5] = f2b(b.y); o[6] = f2b(b.z); o[7] = f2b(b.w);
    *(u16x8*)(Xb + i * 8) = o;
}

// ---------------------------------------------------------------------------
// Weight transpose+convert, z-batched: W[kk][n] fp32 -> Wt[n][kk] bf16.
// R6: optional per-row scale gs[z][kk & 511] (folds rms1 gain g1 into the
// conv2 weights; g per input-feature = K dim = transpose row).
// ---------------------------------------------------------------------------
__global__ __launch_bounds__(256) void transpose_kernel(TransArgs ta, int Ktot)
{
    const float* __restrict__ W  = ta.src[blockIdx.z];
    const float* __restrict__ gs = ta.gs[blockIdx.z];
    ushort*      __restrict__ Wt = ta.dst[blockIdx.z];
    __shared__ float t[32][33];
    const int k0 = blockIdx.x * 32, n0 = blockIdx.y * 32;
    const int r = threadIdx.x >> 5, c = threadIdx.x & 31;
    #pragma unroll
    for (int rr = 0; rr < 4; ++rr) {
        const int kk = k0 + r + rr * 8;
        float v = W[(size_t)kk * 512 + n0 + c];
        if (gs) v *= gs[kk & 511];
        t[r + rr * 8][c] = v;
    }
    __syncthreads();
    #pragma unroll
    for (int rr = 0; rr < 4; ++rr)
        Wt[(size_t)(n0 + r + rr * 8) * Ktot + k0 + c] = f2b(t[c][r + rr * 8]);
}

// ---------------------------------------------------------------------------
// inv1 finalize: inv1[i] = 1/(sqrt(rss[i]/512)+eps)   (i over 3*Mv)
// ---------------------------------------------------------------------------
__global__ __launch_bounds__(256) void finv_kernel(
    const float* __restrict__ rss, float* __restrict__ inv1)
{
    const int i = blockIdx.x * 256 + threadIdx.x;
    inv1[i] = 1.f / (sqrtf(rss[i] * (1.f / 512.f)) + 1e-8f);
}

// ---------------------------------------------------------------------------
// pred finalize: pred[i] = mask ? 0 : sgw[i]/(sqrt(ss2[i]/512)+eps) + bl[z]
// ---------------------------------------------------------------------------
__global__ __launch_bounds__(256) void pred_kernel(
    const float* __restrict__ ss2, const float* __restrict__ sgw,
    const unsigned char* __restrict__ mask,
    const float* __restrict__ bl0, const float* __restrict__ bl1,
    const float* __restrict__ bl2, float* __restrict__ predbase)
{
    const int i = blockIdx.x * 256 + threadIdx.x;
    const int zz = i >> 14;                  // Mv = 2^14
    const int row = i & (Mv - 1);
    const float bl = (zz == 0 ? bl0 : (zz == 1 ? bl1 : bl2))[0];
    const float inv = 1.f / (sqrtf(ss2[i] * (1.f / 512.f)) + 1e-8f);
    predbase[i] = mask[row] ? 0.f : (sgw[i] * inv + bl);
}

// ---------------------------------------------------------------------------
// searchsorted(bins, v, 'left') for pitch & energy targets
// ---------------------------------------------------------------------------
__global__ __launch_bounds__(256) void idx_kernel(
    const float* __restrict__ pt, const float* __restrict__ et,
    const float* __restrict__ pbins, const float* __restrict__ ebins,
    int* __restrict__ idxp, int* __restrict__ idxe)
{
    __shared__ float pb[NBINSv - 1], ebn[NBINSv - 1];
    const int tid = threadIdx.x;
    if (tid < NBINSv - 1) { pb[tid] = pbins[tid]; ebn[tid] = ebins[tid]; }
    __syncthreads();
    const int m = blockIdx.x * 256 + tid;
    const float pv = pt[m], ev = et[m];
    int lo = 0, hi = NBINSv - 1;
    while (lo < hi) { int mid = (lo + hi) >> 1; if (pb[mid] < pv) lo = mid + 1; else hi = mid; }
    idxp[m] = lo;
    lo = 0; hi = NBINSv - 1;
    while (lo < hi) { int mid = (lo + hi) >> 1; if (ebn[mid] < ev) lo = mid + 1; else hi = mid; }
    idxe[m] = lo;
}

// ---------------------------------------------------------------------------
// Per-batch inclusive cumsum of durations, plus mel_len
// ---------------------------------------------------------------------------
__global__ __launch_bounds__(512) void cumsum_kernel(
    const int* __restrict__ dur, int* __restrict__ cum,
    int* __restrict__ melint, float* __restrict__ melout)
{
    __shared__ int s[Lv];
    const int b = blockIdx.x, tid = threadIdx.x;
    s[tid] = dur[b * Lv + tid];
    __syncthreads();
    for (int off = 1; off < Lv; off <<= 1) {
        int t = (tid >= off) ? s[tid - off] : 0;
        __syncthreads();
        s[tid] += t;
        __syncthreads();
    }
    cum[b * Lv + tid] = s[tid];
    if (tid == Lv - 1) { melint[b] = s[tid]; melout[b] = (float)s[tid]; }
}

// ---------------------------------------------------------------------------
// Precompute regulate source map: tmap[b,t] = t < mel_len[b] ? src_row : -1
// ---------------------------------------------------------------------------
__global__ __launch_bounds__(256) void tmap_kernel(
    const int* __restrict__ cum, const int* __restrict__ melint,
    int* __restrict__ tmap)
{
    const int bt = blockIdx.x * 256 + threadIdx.x;
    const int b = bt >> 12;
    const int t = bt & (Tv - 1);
    const int* c = cum + b * Lv;
    int lo = 0, hi = Lv;
    while (lo < hi) { int mid = (lo + hi) >> 1; if (c[mid] <= t) lo = mid + 1; else hi = mid; }
    tmap[bt] = (t < melint[b]) ? (b * Lv + min(lo, Lv - 1)) : -1;
}

// ---------------------------------------------------------------------------
// Length regulate gather: out[bt,:] = tmap[bt] >= 0 ? xo[tmap[bt],:] : 0
// ---------------------------------------------------------------------------
__global__ __launch_bounds__(128) void regulate_kernel(
    const ushort* __restrict__ xo, const int* __restrict__ tmap,
    float* __restrict__ out)
{
    const int bt = blockIdx.x;
    const int src = tmap[bt];
    float4 v = make_float4(0.f, 0.f, 0.f, 0.f);
    if (src >= 0) {
        const ushort4 u = ((const ushort4*)(xo + (size_t)src * 512))[threadIdx.x];
        v.x = b2f(u.x); v.y = b2f(u.y); v.z = b2f(u.z); v.w = b2f(u.w);
    }
    ((float4*)(out + (size_t)bt * 512))[threadIdx.x] = v;
}

// ---------------------------------------------------------------------------
extern "C" void kernel_launch(void* const* d_in, const int* in_sizes, int n_in,
                              void* d_out, int out_size, void* d_ws, size_t ws_size,
                              hipStream_t stream)
{
    const float* x    = (const float*)d_in[0];
    const float* emb  = (const float*)d_in[1];
    const unsigned char* mask = (const unsigned char*)d_in[2];
    const int*   durt = (const int*)d_in[3];
    const float* pt   = (const float*)d_in[4];
    const float* et   = (const float*)d_in[5];
    const float* dw1 = (const float*)d_in[7],  *db1 = (const float*)d_in[8],
               * dg1 = (const float*)d_in[9],  *dw2 = (const float*)d_in[10],
               * db2 = (const float*)d_in[11], *dg2 = (const float*)d_in[12],
               * dwl = (const float*)d_in[13], *dbl = (const float*)d_in[14];
    const float* pw1 = (const float*)d_in[15], *pb1 = (const float*)d_in[16],
               * pg1 = (const float*)d_in[17], *pw2 = (const float*)d_in[18],
               * pb2 = (const float*)d_in[19], *pg2 = (const float*)d_in[20],
               * pwl = (const float*)d_in[21], *pbl = (const float*)d_in[22];
    const float* ew1 = (const float*)d_in[23], *eb1 = (const float*)d_in[24],
               * eg1 = (const float*)d_in[25], *ew2 = (const float*)d_in[26],
               * eb2 = (const float*)d_in[27], *eg2 = (const float*)d_in[28],
               * ewl = (const float*)d_in[29], *ebl = (const float*)d_in[30];
    const float* ppw1 = (const float*)d_in[31], *ppb1 = (const float*)d_in[32],
               * ppw2 = (const float*)d_in[33], *ppb2 = (const float*)d_in[34];
    const float* epw1 = (const float*)d_in[35], *epb1 = (const float*)d_in[36],
               * epw2 = (const float*)d_in[37], *epb2 = (const float*)d_in[38];
    const float* spw1 = (const float*)d_in[39], *spb1 = (const float*)d_in[40],
               * spw2 = (const float*)d_in[41], *spb2 = (const float*)d_in[42];
    const float* pbins = (const float*)d_in[43];
    const float* ebins = (const float*)d_in[44];
    const float* pemb  = (const float*)d_in[45];
    const float* eemb  = (const float*)d_in[46];

    float* outf = (float*)d_out;

    // ---- ws scratch (int offsets) ----
    int*    cum    = (int*)d_ws;                    // 16384
    int*    melint = cum + 16384;                   // 64
    int*    idxp   = melint + 64;                   // 16384
    int*    idxe   = idxp + 16384;                  // 16384
    ushort* zp     = (ushort*)(idxe + 16384);       // 32 ushorts (16B-aligned)
    int*    tmap   = idxe + 16448;                  // 131072
    ushort* xob    = (ushort*)((float*)d_ws + 262144);  // Mv*512 bf16, 1MB offset

    // ---- d_out front scratch (float offsets; regulate overwrites all) ----
    #define OBUF(i) ((ushort*)(outf + (size_t)(i) * 4194304))
    ushort* xb  = OBUF(0);   ushort* eb  = OBUF(1);
    ushort* pA0 = OBUF(2);   ushort* pA1 = OBUF(3);  ushort* pA2 = OBUF(4);
    ushort* xp  = OBUF(5);   ushort* xe  = OBUF(6);
    ushort* c0  = OBUF(7);   ushort* c1  = OBUF(8);  ushort* c2  = OBUF(9);
    // RMS-fold accumulators live in the freed r0 slot (OBUF 10)
    float*  rss  = outf + 10ull * 4194304;          // 3*Mv
    float*  ss2  = rss + 3 * Mv;                    // 3*Mv
    float*  sgw  = rss + 6 * Mv;                    // 3*Mv
    float*  inv1 = rss + 9 * Mv;                    // 3*Mv (written, no memset)
    ushort* wt[12];
    {
        size_t off = 13ull * 4194304;
        for (int i = 0; i < 6; ++i)  { wt[i] = (ushort*)(outf + off); off += 393216; }  // conv 1536x512
        for (int i = 6; i < 12; ++i) { wt[i] = (ushort*)(outf + off); off += 131072; }  // proj 512x512
    }

    hipMemsetAsync(zp, 0, 64, stream);
    hipMemsetAsync(rss, 0, 9ull * Mv * sizeof(float), stream);

    // converts + transposes (batched; conv2 weights scaled by g1 = rms1 fold)
    { ConvArgs ca = {{x, emb}, {xb, eb}};
      convert_kernel<<<dim3(4096, 2), 256, 0, stream>>>(ca); }
    { TransArgs ta = {{dw1, dw2, pw1, pw2, ew1, ew2},
                      {nullptr, dg1, nullptr, pg1, nullptr, eg1},
                      {wt[0], wt[1], wt[2], wt[3], wt[4], wt[5]}};
      transpose_kernel<<<dim3(48, 16, 6), 256, 0, stream>>>(ta, 1536); }
    { TransArgs ta = {{ppw1, ppw2, epw1, epw2, spw1, spw2},
                      {nullptr, nullptr, nullptr, nullptr, nullptr, nullptr},
                      {wt[6], wt[7], wt[8], wt[9], wt[10], wt[11]}};
      transpose_kernel<<<dim3(16, 16, 6), 256, 0, stream>>>(ta, 512); }

    idx_kernel<<<Mv / 256, 256, 0, stream>>>(pt, et, pbins, ebins, idxp, idxe);
    cumsum_kernel<<<Bv, Lv, 0, stream>>>(durt, cum, melint, outf + MEL_OFF);
    tmap_kernel<<<Bv * Tv / 256, 256, 0, stream>>>(cum, melint, tmap);

    const dim3 g3(Fv / 128, Mv / 128, 3);   // (4, 128, 3) = 1536 blocks
    const EpiArgs eaN = {nullptr, nullptr, nullptr, nullptr,
                         {nullptr, nullptr, nullptr}, {nullptr, nullptr, nullptr}};

    // proj1: h = relu(emb @ w1 + b1) for pp/ep/sp
    { GArgs<3> a = {{eb, eb, eb}, {wt[6], wt[8], wt[10]}, {ppb1, epb1, spb1}, {pA0, pA1, pA2}};
      gemm_bf16_kernel<1, 0, 3><<<g3, 256, 0, stream>>>(a, eaN, nullptr, nullptr, nullptr,
                                                        nullptr, nullptr, zp); }
    // proj2 merged: pp/ep -> x + relu(h@w2+b2); sp (z==2) adds pe+ee -> xob
    { GArgs<3> a = {{pA0, pA1, pA2}, {wt[7], wt[9], wt[11]}, {ppb2, epb2, spb2}, {xp, xe, xob}};
      gemm_bf16_kernel<1, 3, 3><<<g3, 256, 0, stream>>>(a, eaN, x, pemb, eemb,
                                                        idxp, idxe, zp); }

    // conv1 for {pit, eng, dur}: write c + accumulate rss (rms1 fold)
    { GArgs<3> a = {{xp, xe, xb}, {wt[2], wt[4], wt[0]}, {pb1, eb1, db1}, {c0, c1, c2}};
      EpiArgs ea = eaN; ea.rss = rss;
      gemm_bf16_kernel<3, 4, 3><<<g3, 256, 0, stream>>>(a, ea, nullptr, nullptr, nullptr,
                                                        nullptr, nullptr, zp); }
    finv_kernel<<<3 * Mv / 256, 256, 0, stream>>>(rss, inv1);
    // conv2 (g1-folded weights): no C write; accumulate ss2/sgw (rmslin fold)
    { GArgs<3> a = {{c0, c1, c2}, {wt[3], wt[5], wt[1]}, {pb2, eb2, db2}, {c0, c1, c2}};
      EpiArgs ea = {nullptr, inv1, ss2, sgw, {pg2, eg2, dg2}, {pwl, ewl, dwl}};
      gemm_bf16_kernel<3, 5, 3><<<g3, 256, 0, stream>>>(a, ea, nullptr, nullptr, nullptr,
                                                        nullptr, nullptr, zp); }
    // pred finalize -> preds at PIT|ENG|DUR (contiguous, z-ordered)
    pred_kernel<<<3 * Mv / 256, 256, 0, stream>>>(ss2, sgw, mask, pbl, ebl, dbl,
                                                  outf + PIT_OFF);

    // length regulate gather -> out (overwrites all d_out-front scratch)
    regulate_kernel<<<Bv * Tv, 128, 0, stream>>>(xob, tmap, outf + OUT_OFF);
}